// Round 15
// baseline (2640.684 us; speedup 1.0000x reference)
//
#include <hip/hip_runtime.h>

#define BB 64
#define SS 2048
#define II 128
#define HH 256
#define OO 128
#define GG 16          // batches per scan block (= MFMA N)
#define RS 264         // f16 row stride per batch-col in LDS (16B aligned)

typedef _Float16 half8 __attribute__((ext_vector_type(8)));
typedef float    f32x4 __attribute__((ext_vector_type(4)));
typedef _Float16 h2_t  __attribute__((ext_vector_type(2)));

#define SC2LOG2E 2.8853900817779268f   // 2*log2(e): exp2(SC*s) = e^{2s}

// ---------------------------------------------------------------------------
// Prep: transpose W_ih -> [I][H] (scaled), W_fc -> [H][O], combined bias
// (scaled), W_hh -> f16 pairs (scaled by 2*log2e so tanh needs no multiply).
// ---------------------------------------------------------------------------
__global__ void prep_kernel(const float* __restrict__ W_ih, const float* __restrict__ b_ih,
                            const float* __restrict__ b_hh, const float* __restrict__ W_fc,
                            float* __restrict__ wihT, float* __restrict__ wfcT,
                            float* __restrict__ biasc, unsigned* __restrict__ whh16,
                            const float* __restrict__ W_hh) {
    int idx = blockIdx.x * 256 + threadIdx.x;
    if (idx < HH * II) {            // W_ih [H][I] -> wihT [I][H], scaled
        int j = idx / II, k = idx % II;
        wihT[k * HH + j] = W_ih[idx] * SC2LOG2E;
    }
    if (idx < OO * HH) {            // W_fc [O][H] -> wfcT [H][O], unscaled
        int j = idx / HH, k = idx % HH;
        wfcT[k * OO + j] = W_fc[idx];
    }
    if (idx < HH * (HH / 2)) {      // W_hh -> packed f16 pairs, scaled
        int j = idx / (HH / 2), i = idx % (HH / 2);
        union { h2_t h; unsigned u; } pk;
        pk.h.x = (_Float16)(W_hh[j * HH + 2 * i]     * SC2LOG2E);
        pk.h.y = (_Float16)(W_hh[j * HH + 2 * i + 1] * SC2LOG2E);
        whh16[idx] = pk.u;
    }
    if (idx < HH) biasc[idx] = (b_ih[idx] + b_hh[idx]) * SC2LOG2E;
}

// ---------------------------------------------------------------------------
// Generic row-major GEMM: C[r][j] = sum_k A[r][k] * Wt[k][j] + bias[j]
// 256 threads, 8x8 micro-tile per thread. (unchanged — scan dominates)
// ---------------------------------------------------------------------------
template<int KD, int JD, int RT>
__global__ __launch_bounds__(256, 2)
void gemm_rk(const float* __restrict__ A, const float* __restrict__ Wt,
             const float* __restrict__ bias, float* __restrict__ C) {
    constexpr int KT = 64;
    constexpr int TJ = JD / 8;
    constexpr int TR = RT / 8;
    static_assert(TJ * TR == 256, "bad tiling");

    __shared__ __align__(16) float a_lds[RT][KT];
    __shared__ __align__(16) float w_lds[KT][JD];

    const int tid = threadIdx.x;
    const int tj = tid % TJ;
    const int tr = tid / TJ;
    const long r0 = (long)blockIdx.x * RT;

    float acc[8][8];
#pragma unroll
    for (int r = 0; r < 8; ++r)
#pragma unroll
        for (int j = 0; j < 8; ++j) acc[r][j] = 0.0f;

    for (int kt = 0; kt < KD; kt += KT) {
        {
            constexpr int NF4 = RT * KT / 4;
#pragma unroll
            for (int f = 0; f < NF4 / 256; ++f) {
                int fl = f * 256 + tid;
                int rr = fl / (KT / 4), kk4 = fl % (KT / 4);
                *(float4*)&a_lds[rr][kk4 * 4] =
                    *(const float4*)&A[(r0 + rr) * KD + kt + kk4 * 4];
            }
        }
        {
            constexpr int NF4 = KT * JD / 4;
#pragma unroll
            for (int f = 0; f < NF4 / 256; ++f) {
                int fl = f * 256 + tid;
                int kk = fl / (JD / 4), jj4 = fl % (JD / 4);
                *(float4*)&w_lds[kk][jj4 * 4] =
                    *(const float4*)&Wt[(long)(kt + kk) * JD + jj4 * 4];
            }
        }
        __syncthreads();

#pragma unroll 4
        for (int k4 = 0; k4 < KT; k4 += 4) {
            float4 xv[8];
#pragma unroll
            for (int r = 0; r < 8; ++r)
                xv[r] = *(const float4*)&a_lds[tr * 8 + r][k4];
#pragma unroll
            for (int i = 0; i < 4; ++i) {
                float4 wa = *(const float4*)&w_lds[k4 + i][tj * 8];
                float4 wb = *(const float4*)&w_lds[k4 + i][tj * 8 + 4];
#pragma unroll
                for (int r = 0; r < 8; ++r) {
                    float xs = (i == 0) ? xv[r].x : (i == 1) ? xv[r].y
                             : (i == 2) ? xv[r].z : xv[r].w;
                    acc[r][0] = fmaf(xs, wa.x, acc[r][0]);
                    acc[r][1] = fmaf(xs, wa.y, acc[r][1]);
                    acc[r][2] = fmaf(xs, wa.z, acc[r][2]);
                    acc[r][3] = fmaf(xs, wa.w, acc[r][3]);
                    acc[r][4] = fmaf(xs, wb.x, acc[r][4]);
                    acc[r][5] = fmaf(xs, wb.y, acc[r][5]);
                    acc[r][6] = fmaf(xs, wb.z, acc[r][6]);
                    acc[r][7] = fmaf(xs, wb.w, acc[r][7]);
                }
            }
        }
        __syncthreads();
    }

    float4 b0 = *(const float4*)&bias[tj * 8];
    float4 b1 = *(const float4*)&bias[tj * 8 + 4];
#pragma unroll
    for (int r = 0; r < 8; ++r) {
        long row = r0 + tr * 8 + r;
        float4 o0, o1;
        o0.x = acc[r][0] + b0.x; o0.y = acc[r][1] + b0.y;
        o0.z = acc[r][2] + b0.z; o0.w = acc[r][3] + b0.w;
        o1.x = acc[r][4] + b1.x; o1.y = acc[r][5] + b1.y;
        o1.z = acc[r][6] + b1.z; o1.w = acc[r][7] + b1.w;
        *(float4*)&C[row * JD + tj * 8]     = o0;
        *(float4*)&C[row * JD + tj * 8 + 4] = o1;
    }
}

// tanh from pre-scaled input: sc = 2*log2e*s  ->  tanh(s) = 1 - 2/(exp2(sc)+1)
__device__ __forceinline__ float tanh_scaled(float sc) {
    float e = exp2f(sc);
    return 1.0f - __fdividef(2.0f, e + 1.0f);
}

// ---------------------------------------------------------------------------
// Sequential scan v8 (MFMA, 8 waves, TRUE depth-2 prefetch):
// H_t[256x16] = tanh(XP_t + W_hh H_{t-1}), in-place over scaled xproj.
// 4 blocks x 512 threads.
//
// v1-v7 lesson (counters + latency arithmetic): the xp "prefetch" used
// register rotation (xp0=xp1; xp1=xp2), whose copies depend on the load
// issued the SAME iteration -> compiler emits s_waitcnt vmcnt(0) in-step:
// effective prefetch depth 0, full L2/L3 latency exposed every step. Fix:
// unroll t by 2 with ping-pong sets; temps are copied at the END of the
// unrolled body (~2 steps after issue), so the vmcnt wait is ~elapsed.
// Also: MFMA dependency split 2x8 -> 4x4 chains (halves dep-chain leg),
// and static h16[0]/h16[1] buffer roles (no dynamic cur).
// ---------------------------------------------------------------------------
__global__ __attribute__((amdgpu_waves_per_eu(2, 2))) __launch_bounds__(512)
void rnn_scan(const unsigned* __restrict__ whh16, float* __restrict__ hid) {
    const int bg  = blockIdx.x;          // batch group (16 batches)
    const int tid = threadIdx.x;
    const int w   = tid >> 6;            // wave 0..7
    const int l   = tid & 63;
    const int c   = l & 15;              // batch col / A-row within tile
    const int q   = l >> 4;              // k-subgroup / D-row group

    __shared__ __align__(16) _Float16 h16[2][GG][RS];

    // A fragments (scaled f16 weights): rows w*32 + rt*16 + c, 8 k-tiles
    half8 a_f[2][8];
#pragma unroll
    for (int rt = 0; rt < 2; ++rt) {
        const unsigned* wp = &whh16[(size_t)(w * 32 + rt * 16 + c) * (HH / 2)];
#pragma unroll
        for (int kt = 0; kt < 8; ++kt)
            a_f[rt][kt] = *(const half8*)&wp[kt * 16 + q * 4];
    }

    // zero both H buffers (h_{-1} = 0)
    for (int i = tid; i < 2 * GG * RS / 2; i += 512) ((unsigned*)h16)[i] = 0u;

    float* __restrict__ basec = hid + (size_t)(bg * GG + c) * SS * HH;
    const int r0 = w * 32 + q * 4;       // D rows: r0 (rt=0), r0+16 (rt=1)

    // ping-pong xp sets: xpA = even step, xpB = odd step (both scaled)
    f32x4 xpA0 = *(const f32x4*)(basec + r0);
    f32x4 xpA1 = *(const f32x4*)(basec + r0 + 16);
    f32x4 xpB0 = *(const f32x4*)(basec + HH + r0);
    f32x4 xpB1 = *(const f32x4*)(basec + HH + r0 + 16);
    __syncthreads();

#define SCAN_STEP(t, RD, WR, X0, X1)                                          \
    do {                                                                      \
        half8 bf[8];                                                          \
        _Pragma("unroll")                                                     \
        for (int kt = 0; kt < 8; ++kt)                                        \
            bf[kt] = *(const half8*)&h16[RD][c][kt * 32 + q * 8];             \
        f32x4 p0a = {0.f,0.f,0.f,0.f}, p0b = p0a, p1a = p0a, p1b = p0a;       \
        _Pragma("unroll")                                                     \
        for (int kt = 0; kt < 4; ++kt) {                                      \
            p0a = __builtin_amdgcn_mfma_f32_16x16x32_f16(a_f[0][kt],   bf[kt],   p0a, 0, 0, 0); \
            p0b = __builtin_amdgcn_mfma_f32_16x16x32_f16(a_f[0][kt+4], bf[kt+4], p0b, 0, 0, 0); \
            p1a = __builtin_amdgcn_mfma_f32_16x16x32_f16(a_f[1][kt],   bf[kt],   p1a, 0, 0, 0); \
            p1b = __builtin_amdgcn_mfma_f32_16x16x32_f16(a_f[1][kt+4], bf[kt+4], p1b, 0, 0, 0); \
        }                                                                     \
        f32x4 s0 = (p0a + p0b) + (X0);                                        \
        f32x4 s1 = (p1a + p1b) + (X1);                                        \
        f32x4 h0, h1;                                                         \
        h0.x = tanh_scaled(s0.x); h0.y = tanh_scaled(s0.y);                   \
        h0.z = tanh_scaled(s0.z); h0.w = tanh_scaled(s0.w);                   \
        h1.x = tanh_scaled(s1.x); h1.y = tanh_scaled(s1.y);                   \
        h1.z = tanh_scaled(s1.z); h1.w = tanh_scaled(s1.w);                   \
        *(f32x4*)(basec + (size_t)(t) * HH + r0)      = h0;                   \
        *(f32x4*)(basec + (size_t)(t) * HH + r0 + 16) = h1;                   \
        union { _Float16 hf[4]; uint2 v; } pk0, pk1;                          \
        pk0.hf[0] = (_Float16)h0.x; pk0.hf[1] = (_Float16)h0.y;               \
        pk0.hf[2] = (_Float16)h0.z; pk0.hf[3] = (_Float16)h0.w;               \
        pk1.hf[0] = (_Float16)h1.x; pk1.hf[1] = (_Float16)h1.y;               \
        pk1.hf[2] = (_Float16)h1.z; pk1.hf[3] = (_Float16)h1.w;               \
        *(uint2*)&h16[WR][c][r0]      = pk0.v;                                \
        *(uint2*)&h16[WR][c][r0 + 16] = pk1.v;                                \
    } while (0)

#pragma unroll 1
    for (int T = 0; T < SS; T += 2) {
        // issue prefetch for T+2 / T+3 FIRST (consumed next unrolled iter;
        // clamped tail loads are never consumed)
        const int t2 = (T + 2 < SS) ? T + 2 : SS - 1;
        const int t3 = (T + 3 < SS) ? T + 3 : SS - 1;
        f32x4 tA0 = *(const f32x4*)(basec + (size_t)t2 * HH + r0);
        f32x4 tA1 = *(const f32x4*)(basec + (size_t)t2 * HH + r0 + 16);
        f32x4 tB0 = *(const f32x4*)(basec + (size_t)t3 * HH + r0);
        f32x4 tB1 = *(const f32x4*)(basec + (size_t)t3 * HH + r0 + 16);

        SCAN_STEP(T,     0, 1, xpA0, xpA1);   // read h16[0], write h16[1]
        __syncthreads();
        SCAN_STEP(T + 1, 1, 0, xpB0, xpB1);   // read h16[1], write h16[0]
        __syncthreads();

        // copies happen ~2 steps after issue -> vmcnt wait mostly elapsed
        xpA0 = tA0; xpA1 = tA1;
        xpB0 = tB0; xpB1 = tB1;
    }
#undef SCAN_STEP
}

// ---------------------------------------------------------------------------
extern "C" void kernel_launch(void* const* d_in, const int* in_sizes, int n_in,
                              void* d_out, int out_size, void* d_ws, size_t ws_size,
                              hipStream_t stream) {
    const float* x    = (const float*)d_in[0];
    const float* W_ih = (const float*)d_in[1];
    const float* W_hh = (const float*)d_in[2];
    const float* b_ih = (const float*)d_in[3];
    const float* b_hh = (const float*)d_in[4];
    const float* W_fc = (const float*)d_in[5];
    const float* b_fc = (const float*)d_in[6];

    float* out_fc  = (float*)d_out;                          // [B][S][O]
    float* hidden  = (float*)d_out + (size_t)BB * SS * OO;   // [B][S][H]

    float*    wihT  = (float*)d_ws;                  // [I][H]  (scaled)
    float*    wfcT  = wihT + II * HH;                // [H][O]
    float*    biasc = wfcT + HH * OO;                // [H]     (scaled)
    unsigned* whh16 = (unsigned*)(biasc + HH);       // [H][H/2] (scaled)

    const long NR = (long)BB * SS;                   // 131072 rows

    prep_kernel<<<128, 256, 0, stream>>>(W_ih, b_ih, b_hh, W_fc,
                                         wihT, wfcT, biasc, whh16, W_hh);
    gemm_rk<II, HH, 64><<<NR / 64, 256, 0, stream>>>(x, wihT, biasc, hidden);
    rnn_scan<<<BB / GG, 512, 0, stream>>>(whh16, hidden);
    gemm_rk<HH, OO, 128><<<NR / 128, 256, 0, stream>>>(hidden, wfcT, b_fc, out_fc);
}

// Round 16
// 1455.659 us; speedup vs baseline: 1.8141x; 1.8141x over previous
//
#include <hip/hip_runtime.h>

#define BB 64
#define SS 2048
#define II 128
#define HH 256
#define OO 128

typedef _Float16 h2_t __attribute__((ext_vector_type(2)));

__device__ __forceinline__ h2_t u2h(unsigned u) {
    union { unsigned u; h2_t h; } c; c.u = u; return c.h;
}

#if __has_builtin(__builtin_amdgcn_fdot2)
__device__ __forceinline__ float fdot2(unsigned h, unsigned w, float acc) {
    return __builtin_amdgcn_fdot2(u2h(h), u2h(w), acc, false);
}
#else
__device__ __forceinline__ float fdot2(unsigned h, unsigned w, float acc) {
    h2_t hh = u2h(h), ww = u2h(w);
    acc = fmaf((float)hh.x, (float)ww.x, acc);
    acc = fmaf((float)hh.y, (float)ww.y, acc);
    return acc;
}
#endif

// ---------------------------------------------------------------------------
// Prep: transpose W_ih -> [I][H], W_fc -> [H][O], combine biases, and write
// the SWIZZLED f16 weight buffer wsw for the scan:
//   slot s = (w*16 + pair*8 + i)*64 + l  holds the dwordx4 that thread
//   (wave w, lane l) consumes as wA[i] (pair=0) / wB[i] (pair=1):
//   row j = w*32 + (l&15)*2 + pair, dwords (l>>4)*32 + i*4 .. +3.
//   -> per-step weight loads are lane-consecutive 16B chunks (coalesced).
// ---------------------------------------------------------------------------
__global__ void prep_kernel(const float* __restrict__ W_ih, const float* __restrict__ b_ih,
                            const float* __restrict__ b_hh, const float* __restrict__ W_fc,
                            float* __restrict__ wihT, float* __restrict__ wfcT,
                            float* __restrict__ biasc, unsigned* __restrict__ wsw,
                            const float* __restrict__ W_hh) {
    int idx = blockIdx.x * 256 + threadIdx.x;      // grid 128*256 = 32768
    if (idx < HH * II) {            // W_ih [H][I] -> wihT [I][H]
        int j = idx / II, k = idx % II;
        wihT[k * HH + j] = W_ih[idx];
    }
    if (idx < OO * HH) {            // W_fc [O][H] -> wfcT [H][O]
        int j = idx / HH, k = idx % HH;
        wfcT[k * OO + j] = W_fc[idx];
    }
    if (idx < HH * (HH / 2)) {      // swizzled scan weights (32768 dwords)
        int d   = idx & 3;
        int s   = idx >> 2;
        int l   = s & 63;
        int rem = s >> 6;
        int i    = rem & 7;
        int pair = (rem >> 3) & 1;
        int w    = rem >> 4;
        int j    = w * 32 + (l & 15) * 2 + pair;
        int word = (l >> 4) * 32 + i * 4 + d;      // dword index within row j
        union { h2_t h; unsigned u; } pk;
        pk.h.x = (_Float16)W_hh[j * HH + 2 * word];
        pk.h.y = (_Float16)W_hh[j * HH + 2 * word + 1];
        wsw[idx] = pk.u;
    }
    if (idx < HH) biasc[idx] = b_ih[idx] + b_hh[idx];
}

// ---------------------------------------------------------------------------
// Generic row-major GEMM: C[r][j] = sum_k A[r][k] * Wt[k][j] + bias[j]
// 256 threads, 8x8 micro-tile per thread. (unchanged — scan dominates)
// ---------------------------------------------------------------------------
template<int KD, int JD, int RT>
__global__ __launch_bounds__(256, 2)
void gemm_rk(const float* __restrict__ A, const float* __restrict__ Wt,
             const float* __restrict__ bias, float* __restrict__ C) {
    constexpr int KT = 64;
    constexpr int TJ = JD / 8;
    constexpr int TR = RT / 8;
    static_assert(TJ * TR == 256, "bad tiling");

    __shared__ __align__(16) float a_lds[RT][KT];
    __shared__ __align__(16) float w_lds[KT][JD];

    const int tid = threadIdx.x;
    const int tj = tid % TJ;
    const int tr = tid / TJ;
    const long r0 = (long)blockIdx.x * RT;

    float acc[8][8];
#pragma unroll
    for (int r = 0; r < 8; ++r)
#pragma unroll
        for (int j = 0; j < 8; ++j) acc[r][j] = 0.0f;

    for (int kt = 0; kt < KD; kt += KT) {
        {
            constexpr int NF4 = RT * KT / 4;
#pragma unroll
            for (int f = 0; f < NF4 / 256; ++f) {
                int fl = f * 256 + tid;
                int rr = fl / (KT / 4), kk4 = fl % (KT / 4);
                *(float4*)&a_lds[rr][kk4 * 4] =
                    *(const float4*)&A[(r0 + rr) * KD + kt + kk4 * 4];
            }
        }
        {
            constexpr int NF4 = KT * JD / 4;
#pragma unroll
            for (int f = 0; f < NF4 / 256; ++f) {
                int fl = f * 256 + tid;
                int kk = fl / (JD / 4), jj4 = fl % (JD / 4);
                *(float4*)&w_lds[kk][jj4 * 4] =
                    *(const float4*)&Wt[(long)(kt + kk) * JD + jj4 * 4];
            }
        }
        __syncthreads();

#pragma unroll 4
        for (int k4 = 0; k4 < KT; k4 += 4) {
            float4 xv[8];
#pragma unroll
            for (int r = 0; r < 8; ++r)
                xv[r] = *(const float4*)&a_lds[tr * 8 + r][k4];
#pragma unroll
            for (int i = 0; i < 4; ++i) {
                float4 wa = *(const float4*)&w_lds[k4 + i][tj * 8];
                float4 wb = *(const float4*)&w_lds[k4 + i][tj * 8 + 4];
#pragma unroll
                for (int r = 0; r < 8; ++r) {
                    float xs = (i == 0) ? xv[r].x : (i == 1) ? xv[r].y
                             : (i == 2) ? xv[r].z : xv[r].w;
                    acc[r][0] = fmaf(xs, wa.x, acc[r][0]);
                    acc[r][1] = fmaf(xs, wa.y, acc[r][1]);
                    acc[r][2] = fmaf(xs, wa.z, acc[r][2]);
                    acc[r][3] = fmaf(xs, wa.w, acc[r][3]);
                    acc[r][4] = fmaf(xs, wb.x, acc[r][4]);
                    acc[r][5] = fmaf(xs, wb.y, acc[r][5]);
                    acc[r][6] = fmaf(xs, wb.z, acc[r][6]);
                    acc[r][7] = fmaf(xs, wb.w, acc[r][7]);
                }
            }
        }
        __syncthreads();
    }

    float4 b0 = *(const float4*)&bias[tj * 8];
    float4 b1 = *(const float4*)&bias[tj * 8 + 4];
#pragma unroll
    for (int r = 0; r < 8; ++r) {
        long row = r0 + tr * 8 + r;
        float4 o0, o1;
        o0.x = acc[r][0] + b0.x; o0.y = acc[r][1] + b0.y;
        o0.z = acc[r][2] + b0.z; o0.w = acc[r][3] + b0.w;
        o1.x = acc[r][4] + b1.x; o1.y = acc[r][5] + b1.y;
        o1.z = acc[r][6] + b1.z; o1.w = acc[r][7] + b1.w;
        *(float4*)&C[row * JD + tj * 8]     = o0;
        *(float4*)&C[row * JD + tj * 8 + 4] = o1;
    }
}

// ---------------------------------------------------------------------------
// Sequential scan v9: v5's structure (best measured, 1362us) with ONE change:
// weights are re-streamed from L2 each step (coalesced loads from the
// swizzled wsw buffer) instead of held in registers.
//
// Rationale (v1-v8 counters): VGPR_Count froze at 84/88/44/88/132/88 across
// five allocator hints; per-active-CU VALUBusy was 2.4-4.5x the source VALU
// count in every version -> any large per-thread state held across the
// barrier+loop is demoted to AGPR/scratch with a copy per use. v9 removes
// the need for residency: per-step 16x global_load_dwordx4 (L2-resident
// 128KB/CU working set, ~23 TB/s aggregate < 34.5 TB/s L2 ceiling), leaving
// ~70 live VGPRs -> nothing to demote. Everything else is v5 verbatim
// (same math, expect absmax == 0.0078125 exactly).
// ---------------------------------------------------------------------------
__global__ __attribute__((amdgpu_waves_per_eu(2, 2))) __launch_bounds__(512)
void rnn_scan(const unsigned* __restrict__ wsw, float* __restrict__ hid) {
    const int b   = blockIdx.x;
    const int tid = threadIdx.x;
    const int w   = tid >> 6;
    const int l   = tid & 63;
    const int sl  = l & 15;
    const int q   = l >> 4;

    const int j0 = w * 32 + sl * 2;      // two outputs j0, j0+1

    __shared__ __align__(16) unsigned h16[2][4 * 36];

    // per-thread weight stream base: lane-consecutive 16B chunks
    const uint4* __restrict__ wp = (const uint4*)wsw + ((size_t)w << 10) + l;

    for (int i = tid; i < 2 * 4 * 36; i += 512) ((unsigned*)h16)[i] = 0u;

    float* __restrict__ base = hid + (size_t)b * SS * HH;
    float2 xp0 = *(const float2*)&base[j0];
    float2 xp1 = *(const float2*)&base[HH + j0];
    __syncthreads();

#pragma unroll 1
    for (int t = 0; t < SS; ++t) {
        // weight stream for this step (L2-resident, coalesced):
        // wA[i] at slot (w*16+i)*64+l, wB[i] at slot (w*16+8+i)*64+l
        uint4 wA[8], wB[8];
#pragma unroll
        for (int i = 0; i < 8; ++i) {
            wA[i] = wp[i * 64];
            wB[i] = wp[(8 + i) * 64];
        }

        // prefetch xproj for t+2 (read precedes the overwrite at t)
        float2 xp2 = make_float2(0.f, 0.f);
        if (t + 2 < SS) xp2 = *(const float2*)&base[(size_t)(t + 2) * HH + j0];

        const uint4* hb = (const uint4*)&h16[t & 1][q * 36];
        float aA0 = 0.f, aA1 = 0.f, aB0 = 0.f, aB1 = 0.f;
#pragma unroll
        for (int i = 0; i < 8; ++i) {
            uint4 hv = hb[i];
            aA0 = fdot2(hv.x, wA[i].x, aA0);
            aA1 = fdot2(hv.y, wA[i].y, aA1);
            aA0 = fdot2(hv.z, wA[i].z, aA0);
            aA1 = fdot2(hv.w, wA[i].w, aA1);
            aB0 = fdot2(hv.x, wB[i].x, aB0);
            aB1 = fdot2(hv.y, wB[i].y, aB1);
            aB0 = fdot2(hv.z, wB[i].z, aB0);
            aB1 = fdot2(hv.w, wB[i].w, aB1);
        }
        float sA = aA0 + aA1;
        float sB = aB0 + aB1;
        // butterfly over the 4 k-quarters (lanes sl, sl+16, sl+32, sl+48)
        sA += __shfl_xor(sA, 16, 64);
        sA += __shfl_xor(sA, 32, 64);
        sB += __shfl_xor(sB, 16, 64);
        sB += __shfl_xor(sB, 32, 64);

        float s0 = xp0.x + sA;
        float s1 = xp0.y + sB;
        // tanh(s) = 1 - 2/(e^{2s}+1); overflow-safe without clamps
        float e0  = __expf(2.0f * s0);
        float e1  = __expf(2.0f * s1);
        float hn0 = 1.0f - __fdividef(2.0f, e0 + 1.0f);
        float hn1 = 1.0f - __fdividef(2.0f, e1 + 1.0f);

        if (q == 0) {
            union { h2_t h; unsigned u; } pk;
            pk.h.x = (_Float16)hn0;
            pk.h.y = (_Float16)hn1;
            const int W = j0 >> 1;
            h16[(t & 1) ^ 1][(W >> 5) * 36 + (W & 31)] = pk.u;
            *(float2*)&base[(size_t)t * HH + j0] = make_float2(hn0, hn1);
        }
        __syncthreads();
        xp0 = xp1;
        xp1 = xp2;
    }
}

// ---------------------------------------------------------------------------
extern "C" void kernel_launch(void* const* d_in, const int* in_sizes, int n_in,
                              void* d_out, int out_size, void* d_ws, size_t ws_size,
                              hipStream_t stream) {
    const float* x    = (const float*)d_in[0];
    const float* W_ih = (const float*)d_in[1];
    const float* W_hh = (const float*)d_in[2];
    const float* b_ih = (const float*)d_in[3];
    const float* b_hh = (const float*)d_in[4];
    const float* W_fc = (const float*)d_in[5];
    const float* b_fc = (const float*)d_in[6];

    float* out_fc  = (float*)d_out;                          // [B][S][O]
    float* hidden  = (float*)d_out + (size_t)BB * SS * OO;   // [B][S][H]

    float*    wihT  = (float*)d_ws;                  // [I][H]  32768 f
    float*    wfcT  = wihT + II * HH;                // [H][O]  32768 f
    float*    biasc = wfcT + HH * OO;                // [H]       256 f
    unsigned* wsw   = (unsigned*)(biasc + HH);       // swizzled [32768] u32

    const long NR = (long)BB * SS;                   // 131072 rows

    prep_kernel<<<128, 256, 0, stream>>>(W_ih, b_ih, b_hh, W_fc,
                                         wihT, wfcT, biasc, wsw, W_hh);
    gemm_rk<II, HH, 64><<<NR / 64, 256, 0, stream>>>(x, wihT, biasc, hidden);
    rnn_scan<<<BB, 512, 0, stream>>>(wsw, hidden);
    gemm_rk<HH, OO, 128><<<NR / 128, 256, 0, stream>>>(hidden, wfcT, b_fc, out_fc);
}